// Round 1
// baseline (1430.613 us; speedup 1.0000x reference)
//
#include <hip/hip_runtime.h>
#include <hip/hip_bf16.h>
#include <stdint.h>

// GCN pose: fused per-sample chain. 64*243=15552 samples, 17 joints, hidden 256, 4 layers.
// Split-bf16 (hi+lo) 3-pass MFMA for fp32-grade accuracy on 32x32x16_bf16 matrix cores.

#define J17   17
#define HID   256
#define NLAY  4
#define NSAMP 15552
#define SPW   5          // samples per workgroup
#define RUSE  85         // SPW*17 used rows
#define RPAD  96         // padded rows (3 row-tiles of 32)
#define NWG   3111       // ceil(NSAMP/SPW)

typedef __attribute__((ext_vector_type(8)))  short  short8;   // 8 x bf16 fragment
typedef __attribute__((ext_vector_type(16))) float  float16;  // 32x32 accumulator

// fixed adjacency sparsity pattern (self + edges); values computed from adj input at runtime
static constexpr int OFS[18] = {0,3,6,9,11,13,17,21,24,27,29,31,35,39,42,45,47,49};
static constexpr int NBRF[49] = {
  0,1,2,  1,0,3,  2,0,4,  3,1,  4,2,
  5,6,7,11,  6,5,8,12,  7,5,9,  8,6,10,  9,7,  10,8,
  11,5,12,13, 12,6,11,14, 13,11,15, 14,12,16, 15,13, 16,14};

__device__ __forceinline__ unsigned short f2bf(float f){
  unsigned u = __builtin_bit_cast(unsigned, f);
  u += 0x7fffu + ((u >> 16) & 1u);           // RNE
  return (unsigned short)(u >> 16);
}
__device__ __forceinline__ float bf2f(unsigned short b){
  return __builtin_bit_cast(float, ((unsigned)b) << 16);
}

// ---------------- prep: A_hat + W split(hi/lo) + tile into fragment order ----------------
// pret layout (ushort): [layer][chunk(8)][hl(2)][u(4)][c(256)][j(8)]
//   element = split(W[layer][k][c], hl) with k = chunk*32 + (u>>1)*16 + (u&1)*8 + j
__global__ __launch_bounds__(256)
void gcn_prep(const float* __restrict__ adj, const float* __restrict__ Ws,
              float* __restrict__ Ahat, unsigned short* __restrict__ pret)
{
  if (blockIdx.x < 1024){
    const int e = blockIdx.x*256 + threadIdx.x;      // e = layer*65536 + k*256 + c
    const float w = Ws[e];
    const unsigned short hi = f2bf(w);
    const unsigned short lo = f2bf(w - bf2f(hi));
    const int layer = e >> 16, k = (e >> 8) & 255, c = e & 255;
    const int chunk = k >> 5, u = (k >> 3) & 3, j = k & 7;
    const size_t base = ((((size_t)(layer*8 + chunk)*2 + 0)*4 + u)*256 + c)*8 + j;
    pret[base]        = hi;
    pret[base + 8192] = lo;                          // hl stride = 4*256*8
  } else {
    for (int t = threadIdx.x; t < 289; t += 256){
      const int j = t/17, k = t%17;
      float dj = 1e-5f, dk = 1e-5f;
      for (int m=0;m<17;++m){ dj += adj[j*17+m]; dk += adj[k*17+m]; }
      Ahat[t] = adj[t] / (sqrtf(dj)*sqrtf(dk));
    }
  }
}

// sparse mix for this half-wave's own C-layout rows (static rows -> static coeffs)
#define MIX_BODY(HH) \
  _Pragma("unroll") \
  for (int rt_=0; rt_<3; ++rt_){ \
    _Pragma("unroll") \
    for (int q_=0; q_<16; ++q_){ \
      const int r_ = rt_*32 + (q_&3) + 8*(q_>>2) + 4*(HH); \
      if (r_ < RUSE){ \
        const int s_ = r_/17, j_ = r_%17; \
        float v_ = bsv; \
        _Pragma("unroll") \
        for (int t_=OFS[j_]; t_<OFS[j_+1]; ++t_) v_ += Ac[t_]*sup[s_*17 + NBRF[t_]]; \
        if (s_ < sv){ \
          const float o_ = fmaxf(v_, 0.0f) + hold[rt_][ct][q_]; \
          hold[rt_][ct][q_] = o_; \
          const int hb_ = (r_ << 9) + ((2*c) ^ ((r_ & 7) << 4)); \
          const unsigned short hi_ = f2bf(o_); \
          h_hi[hb_>>1] = hi_; \
          h_lo[hb_>>1] = f2bf(o_ - bf2f(hi_)); \
        } \
      } \
    } \
  }

__global__ __launch_bounds__(256, 1)
void gcn_main(const float* __restrict__ x, const float* __restrict__ w_in,
              const float* __restrict__ b_in, const float* __restrict__ bs,
              const float* __restrict__ w_out, const float* __restrict__ b_out,
              const float* __restrict__ Ahat, const unsigned short* __restrict__ pret,
              float* __restrict__ out)
{
  __shared__ uint4 smem4[8192];                       // 128 KB
  unsigned short* h_hi = (unsigned short*)smem4;      // [96][256] bf16, swizzled
  unsigned short* h_lo = h_hi + 24576;
  unsigned short* stg  = h_hi + 49152;                // 32 KB W-chunk stage

  const int tid  = threadIdx.x;
  const int lane = tid & 63;
  const int wid  = tid >> 6;
  const int kh   = lane >> 5;
  const int l31  = lane & 31;
  const int wg   = blockIdx.x;
  const int sv   = min(SPW, NSAMP - wg*SPW);

  // sparse A_hat coefficients (uniform loads -> SGPRs)
  float Ac[49];
#pragma unroll
  for (int j=0;j<17;++j){
#pragma unroll
    for (int t=OFS[j]; t<OFS[j+1]; ++t) Ac[t] = Ahat[j*17 + NBRF[t]];
  }

  // -------- input projection: h = x @ w_in + b_in (thread tid = channel) --------
  {
    const float w0 = w_in[tid], w1 = w_in[256+tid], w2 = w_in[512+tid], bc = b_in[tid];
#pragma unroll 1
    for (int s=0; s<SPW; ++s){
      const bool v = (s < sv);
      const size_t xb = ((size_t)(wg*SPW+s))*51;
#pragma unroll 1
      for (int j=0;j<J17;++j){
        float hv = 0.0f;
        if (v) hv = bc + x[xb + j*3]*w0 + x[xb + j*3 + 1]*w1 + x[xb + j*3 + 2]*w2;
        const int r = s*17 + j;
        const int hb = (r << 9) + ((2*tid) ^ ((r & 7) << 4));
        const unsigned short hi = f2bf(hv);
        h_hi[hb >> 1] = hi;
        h_lo[hb >> 1] = f2bf(hv - bf2f(hi));
      }
    }
#pragma unroll 1
    for (int r=RUSE; r<RPAD; ++r){                    // zero pad rows
      const int hb = (r << 9) + ((2*tid) ^ ((r & 7) << 4));
      h_hi[hb >> 1] = 0; h_lo[hb >> 1] = 0;
    }
  }
  __syncthreads();

  // residual kept in registers in C-fragment layout
  float16 hold[3][2];
#pragma unroll
  for (int rt=0; rt<3; ++rt)
#pragma unroll
  for (int ct=0; ct<2; ++ct){
    const int c = wid*64 + ct*32 + l31;
#pragma unroll
    for (int q=0; q<16; ++q){
      const int r = rt*32 + (q&3) + 8*(q>>2) + 4*kh;
      const int hb = (r << 9) + ((2*c) ^ ((r & 7) << 4));
      hold[rt][ct][q] = bf2f(h_hi[hb>>1]) + bf2f(h_lo[hb>>1]);
    }
  }

  // ---------------------------- layers ----------------------------
#pragma unroll 1
  for (int layer=0; layer<NLAY; ++layer){
    float16 acc[3][2];
#pragma unroll
    for (int rt=0;rt<3;++rt)
#pragma unroll
    for (int ct=0;ct<2;++ct)
#pragma unroll
    for (int q=0;q<16;++q) acc[rt][ct][q] = 0.0f;

#pragma unroll 1
    for (int chunk=0; chunk<8; ++chunk){
      __syncthreads();
      {
        const uint4* s4 = (const uint4*)(pret) + (size_t)(layer*8+chunk)*2048;
        uint4* d4 = (uint4*)(stg);
#pragma unroll
        for (int i=0;i<8;++i) d4[tid + i*256] = s4[tid + i*256];
      }
      __syncthreads();
#pragma unroll
      for (int sub=0; sub<2; ++sub){
        const int kk = chunk*2 + sub;
        short8 Ahi[3], Alo[3];
#pragma unroll
        for (int rt=0; rt<3; ++rt){
          const int r = rt*32 + l31;
          const int off = (kk*32 + kh*16) ^ ((r & 7) << 4);
          Ahi[rt] = *(const short8*)((const char*)h_hi + (r << 9) + off);
          Alo[rt] = *(const short8*)((const char*)h_lo + (r << 9) + off);
        }
        short8 Bhi[2], Blo[2];
#pragma unroll
        for (int ct=0; ct<2; ++ct){
          const int c = wid*64 + ct*32 + l31;
          const int so = (sub*2 + kh)*4096 + c*16;
          Bhi[ct] = *(const short8*)((const char*)stg + so);
          Blo[ct] = *(const short8*)((const char*)stg + 16384 + so);
        }
#pragma unroll
        for (int rt=0; rt<3; ++rt)
#pragma unroll
        for (int ct=0; ct<2; ++ct){
          acc[rt][ct] = __builtin_amdgcn_mfma_f32_32x32x16_bf16(Ahi[rt], Bhi[ct], acc[rt][ct], 0,0,0);
          acc[rt][ct] = __builtin_amdgcn_mfma_f32_32x32x16_bf16(Ahi[rt], Blo[ct], acc[rt][ct], 0,0,0);
          acc[rt][ct] = __builtin_amdgcn_mfma_f32_32x32x16_bf16(Alo[rt], Bhi[ct], acc[rt][ct], 0,0,0);
        }
      }
    }
    __syncthreads();   // all A-frag reads done before mix rewrites h

    // -------- graph mix + bias + relu + residual, update h --------
#pragma unroll
    for (int ct=0; ct<2; ++ct){
      const int c = wid*64 + ct*32 + l31;
      const float bsv = bs[layer*256 + c];
      float sup[96];
#pragma unroll
      for (int rt=0; rt<3; ++rt){
#pragma unroll
        for (int q=0; q<16; ++q){
          const float own = acc[rt][ct][q];
          const float oth = __shfl_xor(own, 32, 64);
          const int rb = rt*32 + (q&3) + 8*(q>>2);
          sup[rb]   = kh ? oth : own;
          sup[rb+4] = kh ? own : oth;
        }
      }
      if (kh == 0){
        MIX_BODY(0)
      } else {
        MIX_BODY(1)
      }
    }
  }

  __syncthreads();

  // -------- output projection: y = h @ w_out + b_out --------
  {
    float wo0[4], wo1[4], wo2[4];
#pragma unroll
    for (int i=0;i<4;++i){
      const int k = i*64 + lane;
      wo0[i] = w_out[k*3]; wo1[i] = w_out[k*3+1]; wo2[i] = w_out[k*3+2];
    }
    const float bo0=b_out[0], bo1=b_out[1], bo2=b_out[2];
#pragma unroll 1
    for (int s=0; s<SPW; ++s){
      if (s >= sv) break;
#pragma unroll 1
      for (int j=0; j<J17; ++j){
        const int r = s*17 + j;
        if ((r & 3) != wid) continue;
        float p0=0.f, p1=0.f, p2=0.f;
#pragma unroll
        for (int i=0;i<4;++i){
          const int k = i*64 + lane;
          const int hb = (r << 9) + ((2*k) ^ ((r & 7) << 4));
          const float hv = bf2f(h_hi[hb>>1]) + bf2f(h_lo[hb>>1]);
          p0 += hv*wo0[i]; p1 += hv*wo1[i]; p2 += hv*wo2[i];
        }
#pragma unroll
        for (int m=32; m>0; m>>=1){
          p0 += __shfl_xor(p0, m, 64);
          p1 += __shfl_xor(p1, m, 64);
          p2 += __shfl_xor(p2, m, 64);
        }
        if (lane == 0){
          const size_t o = ((size_t)(wg*SPW+s)*17 + j)*3;
          out[o] = p0 + bo0; out[o+1] = p1 + bo1; out[o+2] = p2 + bo2;
        }
      }
    }
  }
}

extern "C" void kernel_launch(void* const* d_in, const int* in_sizes, int n_in,
                              void* d_out, int out_size, void* d_ws, size_t ws_size,
                              hipStream_t stream)
{
  const float* x     = (const float*)d_in[0];
  const float* adj   = (const float*)d_in[1];
  const float* w_in  = (const float*)d_in[2];
  const float* b_in  = (const float*)d_in[3];
  const float* Ws    = (const float*)d_in[4];
  const float* bs    = (const float*)d_in[5];
  const float* w_out = (const float*)d_in[6];
  const float* b_out = (const float*)d_in[7];
  float* out = (float*)d_out;

  float* Ahat = (float*)d_ws;
  unsigned short* pret = (unsigned short*)((char*)d_ws + 4096);   // 1 MB

  hipLaunchKernelGGL(gcn_prep, dim3(1025), dim3(256), 0, stream, adj, Ws, Ahat, pret);
  hipLaunchKernelGGL(gcn_main, dim3(NWG), dim3(256), 0, stream,
                     x, w_in, b_in, bs, w_out, b_out, Ahat, pret, out);
}

// Round 2
// 759.862 us; speedup vs baseline: 1.8827x; 1.8827x over previous
//
#include <hip/hip_runtime.h>
#include <hip/hip_bf16.h>
#include <stdint.h>

// GCN pose: fused per-sample chain. 64*243=15552 samples, 17 joints, hidden 256, 4 layers.
// Split-bf16 (hi+lo) 3-pass MFMA. Round 2: 512 threads (2 waves/SIMD), B-frags direct
// from global (no LDS stage, no staging barriers), full (r&31)<<4 LDS swizzle.

#define J17   17
#define HID   256
#define NLAY  4
#define NSAMP 15552
#define SPW   5          // samples per workgroup
#define RUSE  85         // SPW*17 used rows
#define RPAD  96         // padded rows (3 row-tiles of 32)
#define NWG   3111       // ceil(NSAMP/SPW)

typedef __attribute__((ext_vector_type(8)))  short  short8;   // 8 x bf16 fragment
typedef __attribute__((ext_vector_type(16))) float  float16;  // 32x32 accumulator

// fixed adjacency sparsity pattern (self + edges); values computed from adj input at runtime
static constexpr int OFS[18] = {0,3,6,9,11,13,17,21,24,27,29,31,35,39,42,45,47,49};
static constexpr int NBRF[49] = {
  0,1,2,  1,0,3,  2,0,4,  3,1,  4,2,
  5,6,7,11,  6,5,8,12,  7,5,9,  8,6,10,  9,7,  10,8,
  11,5,12,13, 12,6,11,14, 13,11,15, 14,12,16, 15,13, 16,14};

__device__ __forceinline__ unsigned short f2bf(float f){
  unsigned u = __builtin_bit_cast(unsigned, f);
  u += 0x7fffu + ((u >> 16) & 1u);           // RNE
  return (unsigned short)(u >> 16);
}
__device__ __forceinline__ float bf2f(unsigned short b){
  return __builtin_bit_cast(float, ((unsigned)b) << 16);
}

// ---------------- prep: A_hat + W split(hi/lo) + tile into fragment order ----------------
// pret layout (ushort): [layer][chunk(8)][hl(2)][u(4)][c(256)][j(8)]
//   element = split(W[layer][k][c], hl) with k = chunk*32 + (u>>1)*16 + (u&1)*8 + j
__global__ __launch_bounds__(256)
void gcn_prep(const float* __restrict__ adj, const float* __restrict__ Ws,
              float* __restrict__ Ahat, unsigned short* __restrict__ pret)
{
  if (blockIdx.x < 1024){
    const int e = blockIdx.x*256 + threadIdx.x;      // e = layer*65536 + k*256 + c
    const float w = Ws[e];
    const unsigned short hi = f2bf(w);
    const unsigned short lo = f2bf(w - bf2f(hi));
    const int layer = e >> 16, k = (e >> 8) & 255, c = e & 255;
    const int chunk = k >> 5, u = (k >> 3) & 3, j = k & 7;
    const size_t base = ((((size_t)(layer*8 + chunk)*2 + 0)*4 + u)*256 + c)*8 + j;
    pret[base]        = hi;
    pret[base + 8192] = lo;                          // hl stride = 4*256*8
  } else {
    for (int t = threadIdx.x; t < 289; t += 256){
      const int j = t/17, k = t%17;
      float dj = 1e-5f, dk = 1e-5f;
      for (int m=0;m<17;++m){ dj += adj[j*17+m]; dk += adj[k*17+m]; }
      Ahat[t] = adj[t] / (sqrtf(dj)*sqrtf(dk));
    }
  }
}

// sparse mix for this half-wave's own C-layout rows (static rows -> static coeffs)
#define MIX_BODY(HH) \
  _Pragma("unroll") \
  for (int rt_=0; rt_<3; ++rt_){ \
    _Pragma("unroll") \
    for (int q_=0; q_<16; ++q_){ \
      const int r_ = rt_*32 + (q_&3) + 8*(q_>>2) + 4*(HH); \
      if (r_ < RUSE){ \
        const int s_ = r_/17, j_ = r_%17; \
        float v_ = bsv; \
        _Pragma("unroll") \
        for (int t_=OFS[j_]; t_<OFS[j_+1]; ++t_) v_ += Ac[t_]*sup[s_*17 + NBRF[t_]]; \
        if (s_ < sv){ \
          const float o_ = fmaxf(v_, 0.0f) + hold[rt_][q_]; \
          hold[rt_][q_] = o_; \
          const int hb_ = (r_ << 9) + ((2*c) ^ ((r_ & 31) << 4)); \
          const unsigned short hi_ = f2bf(o_); \
          h_hi[hb_>>1] = hi_; \
          h_lo[hb_>>1] = f2bf(o_ - bf2f(hi_)); \
        } \
      } \
    } \
  }

__global__ __launch_bounds__(512, 2)
void gcn_main(const float* __restrict__ x, const float* __restrict__ w_in,
              const float* __restrict__ b_in, const float* __restrict__ bs,
              const float* __restrict__ w_out, const float* __restrict__ b_out,
              const float* __restrict__ Ahat, const unsigned short* __restrict__ pret,
              float* __restrict__ out)
{
  __shared__ unsigned short h_hi[RPAD*HID];   // 48 KB, swizzled (r&31)<<4
  __shared__ unsigned short h_lo[RPAD*HID];   // 48 KB

  const int tid  = threadIdx.x;
  const int lane = tid & 63;
  const int wid  = tid >> 6;         // 0..7 : column-slice owner
  const int kh   = lane >> 5;
  const int l31  = lane & 31;
  const int c    = wid*32 + l31;     // this thread's output column
  const int wg   = blockIdx.x;
  const int sv   = min(SPW, NSAMP - wg*SPW);

  const char* h_hi_b = (const char*)h_hi;
  const char* h_lo_b = (const char*)h_lo;

  // ---- B prefetch machinery: frags straight from global (L2-resident) ----
  const short8* pret8 = (const short8*)pret;            // 16B granules
  const int bbase = kh*256 + c;                          // per-thread offset
  short8 BA[4], BB[4];                                   // {s0hi, s0lo, s1hi, s1lo}
  auto loadB = [&](int lc, short8* dst){                 // lc = layer*8 + chunk (clamped)
    const short8* p = pret8 + (size_t)lc*2048 + bbase;
    dst[0] = p[0];
    dst[1] = p[1024];
    dst[2] = p[512];
    dst[3] = p[1536];
  };
  loadB(0, BA);                                          // hide L2 latency under prologue

  // sparse A_hat coefficients -> force SGPRs
  float Ac[49];
#pragma unroll
  for (int j=0;j<17;++j){
#pragma unroll
    for (int t=OFS[j]; t<OFS[j+1]; ++t){
      const float a = Ahat[j*17 + NBRF[t]];
      Ac[t] = __builtin_bit_cast(float,
                __builtin_amdgcn_readfirstlane(__builtin_bit_cast(int, a)));
    }
  }

  // -------- input projection directly in C-fragment ownership --------
  float16 hold[3];
  {
    const float bc  = b_in[c];
    const float wi0 = w_in[c], wi1 = w_in[256+c], wi2 = w_in[512+c];
#pragma unroll
    for (int rt=0; rt<3; ++rt){
#pragma unroll
      for (int q=0; q<16; ++q){
        const int r = rt*32 + (q&3) + 8*(q>>2) + 4*kh;
        float hv = 0.0f;
        if (r < RUSE){
          const int s = r/17, j = r%17;
          if (s < sv){
            const size_t xb = ((size_t)(wg*SPW + s))*51 + j*3;
            hv = bc + x[xb]*wi0 + x[xb+1]*wi1 + x[xb+2]*wi2;
          }
        }
        hold[rt][q] = hv;
        const int hb = (r << 9) + ((2*c) ^ ((r & 31) << 4));
        const unsigned short hi = f2bf(hv);
        h_hi[hb >> 1] = hi;
        h_lo[hb >> 1] = f2bf(hv - bf2f(hi));
      }
    }
  }
  __syncthreads();

  // ---------------------------- layers ----------------------------
  float16 acc[3];
  auto computeChunk = [&](int chunk, const short8* B){
#pragma unroll
    for (int sub=0; sub<2; ++sub){
      const int koff = (chunk*2 + sub)*32 + kh*16;       // byte offset of k-slice
      short8 Ahi[3], Alo[3];
#pragma unroll
      for (int rt=0; rt<3; ++rt){
        const int r   = rt*32 + l31;
        const int off = (r << 9) + (koff ^ ((r & 31) << 4));
        Ahi[rt] = *(const short8*)(h_hi_b + off);
        Alo[rt] = *(const short8*)(h_lo_b + off);
      }
      const short8 Bhi = B[sub*2], Blo = B[sub*2+1];
#pragma unroll
      for (int rt=0; rt<3; ++rt){
        acc[rt] = __builtin_amdgcn_mfma_f32_32x32x16_bf16(Ahi[rt], Bhi, acc[rt], 0,0,0);
        acc[rt] = __builtin_amdgcn_mfma_f32_32x32x16_bf16(Ahi[rt], Blo, acc[rt], 0,0,0);
        acc[rt] = __builtin_amdgcn_mfma_f32_32x32x16_bf16(Alo[rt], Bhi, acc[rt], 0,0,0);
      }
    }
  };

#pragma unroll 1
  for (int layer=0; layer<NLAY; ++layer){
#pragma unroll
    for (int rt=0; rt<3; ++rt)
#pragma unroll
    for (int q=0; q<16; ++q) acc[rt][q] = 0.0f;

#pragma unroll
    for (int cp=0; cp<4; ++cp){
      const int lc = layer*8 + cp*2;
      loadB(min(lc+1, 31), BB);
      computeChunk(cp*2,   BA);
      loadB(min(lc+2, 31), BA);                          // next chunk (or next layer c0)
      computeChunk(cp*2+1, BB);
    }
    __syncthreads();   // all A-frag reads done before mix rewrites h

    // -------- graph mix + bias + relu + residual, update h --------
    {
      const float bsv = bs[layer*256 + c];
      float sup[96];
#pragma unroll
      for (int rt=0; rt<3; ++rt){
#pragma unroll
        for (int q=0; q<16; ++q){
          const float own = acc[rt][q];
          const float oth = __shfl_xor(own, 32, 64);
          const int rb = rt*32 + (q&3) + 8*(q>>2);
          sup[rb]   = kh ? oth : own;
          sup[rb+4] = kh ? own : oth;
        }
      }
      if (kh == 0){
        MIX_BODY(0)
      } else {
        MIX_BODY(1)
      }
    }
    __syncthreads();
  }

  // -------- output projection: y = h @ w_out + b_out --------
  {
    float wo0[4], wo1[4], wo2[4];
#pragma unroll
    for (int i=0;i<4;++i){
      const int k = i*64 + lane;
      wo0[i] = w_out[k*3]; wo1[i] = w_out[k*3+1]; wo2[i] = w_out[k*3+2];
    }
    const float bo0=b_out[0], bo1=b_out[1], bo2=b_out[2];
#pragma unroll 1
    for (int r = wid; r < RUSE; r += 8){
      const int s = r/17, j = r%17;
      if (s >= sv) continue;
      float p0=0.f, p1=0.f, p2=0.f;
#pragma unroll
      for (int i=0;i<4;++i){
        const int k  = i*64 + lane;
        const int hb = (r << 9) + ((2*k) ^ ((r & 31) << 4));
        const float hv = bf2f(h_hi[hb>>1]) + bf2f(h_lo[hb>>1]);
        p0 += hv*wo0[i]; p1 += hv*wo1[i]; p2 += hv*wo2[i];
      }
#pragma unroll
      for (int m=32; m>0; m>>=1){
        p0 += __shfl_xor(p0, m, 64);
        p1 += __shfl_xor(p1, m, 64);
        p2 += __shfl_xor(p2, m, 64);
      }
      if (lane == 0){
        const size_t o = ((size_t)(wg*SPW+s)*17 + j)*3;
        out[o] = p0 + bo0; out[o+1] = p1 + bo1; out[o+2] = p2 + bo2;
      }
    }
  }
}

extern "C" void kernel_launch(void* const* d_in, const int* in_sizes, int n_in,
                              void* d_out, int out_size, void* d_ws, size_t ws_size,
                              hipStream_t stream)
{
  const float* x     = (const float*)d_in[0];
  const float* adj   = (const float*)d_in[1];
  const float* w_in  = (const float*)d_in[2];
  const float* b_in  = (const float*)d_in[3];
  const float* Ws    = (const float*)d_in[4];
  const float* bs    = (const float*)d_in[5];
  const float* w_out = (const float*)d_in[6];
  const float* b_out = (const float*)d_in[7];
  float* out = (float*)d_out;

  float* Ahat = (float*)d_ws;
  unsigned short* pret = (unsigned short*)((char*)d_ws + 4096);   // 1 MB

  hipLaunchKernelGGL(gcn_prep, dim3(1025), dim3(256), 0, stream, adj, Ws, Ahat, pret);
  hipLaunchKernelGGL(gcn_main, dim3(NWG), dim3(512), 0, stream,
                     x, w_in, b_in, bs, w_out, b_out, Ahat, pret, out);
}

// Round 3
// 625.976 us; speedup vs baseline: 2.2854x; 1.2139x over previous
//
#include <hip/hip_runtime.h>
#include <hip/hip_bf16.h>
#include <stdint.h>

// GCN pose: fused per-sample chain. 64*243=15552 samples, 17 joints, hidden 256, 4 layers.
// Split-bf16 (hi+lo) 3-pass MFMA. Round 3: SPW=3 (64 rows, 64KB LDS) -> 2 WGs/CU,
// 4 waves/SIMD; register diet (hold re-read from LDS, cvt-based bf16 split) to fit
// 128 VGPR at __launch_bounds__(512,4). 15552 % 3 == 0 -> no tail logic.

#define J17   17
#define HID   256
#define NLAY  4
#define NSAMP 15552
#define SPW   3          // samples per workgroup
#define RUSE  51         // SPW*17 used rows
#define RPAD  64         // padded rows (2 row-tiles of 32)
#define NWG   5184       // NSAMP/SPW exactly

typedef __attribute__((ext_vector_type(8)))  short  short8;   // 8 x bf16 fragment
typedef __attribute__((ext_vector_type(16))) float  float16;  // 32x32 accumulator

// fixed adjacency sparsity pattern (self + edges); values computed from adj input at runtime
static constexpr int OFS[18] = {0,3,6,9,11,13,17,21,24,27,29,31,35,39,42,45,47,49};
static constexpr int NBRF[49] = {
  0,1,2,  1,0,3,  2,0,4,  3,1,  4,2,
  5,6,7,11,  6,5,8,12,  7,5,9,  8,6,10,  9,7,  10,8,
  11,5,12,13, 12,6,11,14, 13,11,15, 14,12,16, 15,13, 16,14};

__device__ __forceinline__ unsigned short f2bf(float f){
  return __bfloat16_as_ushort(__float2bfloat16(f));   // single v_cvt, RNE
}
__device__ __forceinline__ float bf2f(unsigned short b){
  return __builtin_bit_cast(float, ((unsigned)b) << 16);
}

// ---------------- prep: A_hat + W split(hi/lo) + tile into fragment order ----------------
// pret layout (ushort): [layer][chunk(8)][hl(2)][u(4)][c(256)][j(8)]
//   element = split(W[layer][k][c], hl) with k = chunk*32 + (u>>1)*16 + (u&1)*8 + j
__global__ __launch_bounds__(256)
void gcn_prep(const float* __restrict__ adj, const float* __restrict__ Ws,
              float* __restrict__ Ahat, unsigned short* __restrict__ pret)
{
  if (blockIdx.x < 1024){
    const int e = blockIdx.x*256 + threadIdx.x;      // e = layer*65536 + k*256 + c
    const float w = Ws[e];
    const unsigned short hi = f2bf(w);
    const unsigned short lo = f2bf(w - bf2f(hi));
    const int layer = e >> 16, k = (e >> 8) & 255, c = e & 255;
    const int chunk = k >> 5, u = (k >> 3) & 3, j = k & 7;
    const size_t base = ((((size_t)(layer*8 + chunk)*2 + 0)*4 + u)*256 + c)*8 + j;
    pret[base]        = hi;
    pret[base + 8192] = lo;                          // hl stride = 4*256*8
  } else {
    for (int t = threadIdx.x; t < 289; t += 256){
      const int j = t/17, k = t%17;
      float dj = 1e-5f, dk = 1e-5f;
      for (int m=0;m<17;++m){ dj += adj[j*17+m]; dk += adj[k*17+m]; }
      Ahat[t] = adj[t] / (sqrtf(dj)*sqrtf(dk));
    }
  }
}

// sparse mix for this half-wave's own C-layout rows (static rows -> static coeffs)
#define MIX_BODY(HH) \
  _Pragma("unroll") \
  for (int rt_=0; rt_<2; ++rt_){ \
    _Pragma("unroll") \
    for (int q_=0; q_<16; ++q_){ \
      const int r_ = rt_*32 + (q_&3) + 8*(q_>>2) + 4*(HH); \
      if (r_ < RUSE){ \
        const int s_ = r_/17, j_ = r_%17; \
        float v_ = bsv; \
        _Pragma("unroll") \
        for (int t_=OFS[j_]; t_<OFS[j_+1]; ++t_) v_ += Ac[t_]*sup[s_*17 + NBRF[t_]]; \
        const int hb_ = (r_ << 9) + ((2*c) ^ ((r_ & 31) << 4)); \
        const float o_ = fmaxf(v_, 0.0f) \
                       + bf2f(h_hi[hb_>>1]) + bf2f(h_lo[hb_>>1]); \
        const unsigned short hi_ = f2bf(o_); \
        h_hi[hb_>>1] = hi_; \
        h_lo[hb_>>1] = f2bf(o_ - bf2f(hi_)); \
      } \
    } \
  }

__global__ __launch_bounds__(512, 4)
void gcn_main(const float* __restrict__ x, const float* __restrict__ w_in,
              const float* __restrict__ b_in, const float* __restrict__ bs,
              const float* __restrict__ w_out, const float* __restrict__ b_out,
              const float* __restrict__ Ahat, const unsigned short* __restrict__ pret,
              float* __restrict__ out)
{
  __shared__ unsigned short h_hi[RPAD*HID];   // 32 KB, swizzled (r&31)<<4
  __shared__ unsigned short h_lo[RPAD*HID];   // 32 KB

  const int tid  = threadIdx.x;
  const int lane = tid & 63;
  const int wid  = tid >> 6;         // 0..7 : column-slice owner
  const int kh   = lane >> 5;
  const int l31  = lane & 31;
  const int c    = wid*32 + l31;     // this thread's output column
  const int wg   = blockIdx.x;

  const char* h_hi_b = (const char*)h_hi;
  const char* h_lo_b = (const char*)h_lo;

  // ---- B prefetch machinery: frags straight from global (L2-resident) ----
  const short8* pret8 = (const short8*)pret;            // 16B granules
  const int bbase = kh*256 + c;                          // per-thread offset
  short8 BA[4], BB[4];                                   // {s0hi, s0lo, s1hi, s1lo}
  auto loadB = [&](int lc, short8* dst){                 // lc = layer*8 + chunk (clamped)
    const short8* p = pret8 + (size_t)lc*2048 + bbase;
    dst[0] = p[0];
    dst[1] = p[1024];
    dst[2] = p[512];
    dst[3] = p[1536];
  };
  loadB(0, BA);                                          // hide L2 latency under prologue

  // sparse A_hat coefficients -> force SGPRs
  float Ac[49];
#pragma unroll
  for (int j=0;j<17;++j){
#pragma unroll
    for (int t=OFS[j]; t<OFS[j+1]; ++t){
      const float a = Ahat[j*17 + NBRF[t]];
      Ac[t] = __builtin_bit_cast(float,
                __builtin_amdgcn_readfirstlane(__builtin_bit_cast(int, a)));
    }
  }

  // -------- input projection directly in C-fragment ownership --------
  {
    const float bc  = b_in[c];
    const float wi0 = w_in[c], wi1 = w_in[256+c], wi2 = w_in[512+c];
#pragma unroll
    for (int rt=0; rt<2; ++rt){
#pragma unroll
      for (int q=0; q<16; ++q){
        const int r = rt*32 + (q&3) + 8*(q>>2) + 4*kh;
        float hv = 0.0f;
        if (r < RUSE){
          const int s = r/17, j = r%17;
          const size_t xb = ((size_t)(wg*SPW + s))*51 + j*3;
          hv = bc + x[xb]*wi0 + x[xb+1]*wi1 + x[xb+2]*wi2;
        }
        const int hb = (r << 9) + ((2*c) ^ ((r & 31) << 4));
        const unsigned short hi = f2bf(hv);
        h_hi[hb >> 1] = hi;
        h_lo[hb >> 1] = f2bf(hv - bf2f(hi));
      }
    }
  }
  __syncthreads();

  // ---------------------------- layers ----------------------------
  float16 acc[2];
  auto computeChunk = [&](int chunk, const short8* B){
#pragma unroll
    for (int sub=0; sub<2; ++sub){
      const int koff = (chunk*2 + sub)*32 + kh*16;       // byte offset of k-slice
      short8 Ahi[2], Alo[2];
#pragma unroll
      for (int rt=0; rt<2; ++rt){
        const int r   = rt*32 + l31;
        const int off = (r << 9) + (koff ^ ((r & 31) << 4));
        Ahi[rt] = *(const short8*)(h_hi_b + off);
        Alo[rt] = *(const short8*)(h_lo_b + off);
      }
      const short8 Bhi = B[sub*2], Blo = B[sub*2+1];
#pragma unroll
      for (int rt=0; rt<2; ++rt){
        acc[rt] = __builtin_amdgcn_mfma_f32_32x32x16_bf16(Ahi[rt], Bhi, acc[rt], 0,0,0);
        acc[rt] = __builtin_amdgcn_mfma_f32_32x32x16_bf16(Ahi[rt], Blo, acc[rt], 0,0,0);
        acc[rt] = __builtin_amdgcn_mfma_f32_32x32x16_bf16(Alo[rt], Bhi, acc[rt], 0,0,0);
      }
    }
  };

#pragma unroll 1
  for (int layer=0; layer<NLAY; ++layer){
#pragma unroll
    for (int rt=0; rt<2; ++rt)
#pragma unroll
    for (int q=0; q<16; ++q) acc[rt][q] = 0.0f;

#pragma unroll
    for (int cp=0; cp<4; ++cp){
      const int lc = layer*8 + cp*2;
      loadB(min(lc+1, 31), BB);
      computeChunk(cp*2,   BA);
      loadB(min(lc+2, 31), BA);                          // next chunk (or next layer c0)
      computeChunk(cp*2+1, BB);
    }
    __syncthreads();   // all A-frag reads done before anyone rewrites h

    // -------- graph mix + bias + relu + residual, update h --------
    // (h reads/writes below are owner-only -> race-free after the barrier)
    {
      const float bsv = bs[layer*256 + c];
      float sup[RPAD];
#pragma unroll
      for (int rt=0; rt<2; ++rt){
#pragma unroll
        for (int q=0; q<16; ++q){
          const float own = acc[rt][q];
          const float oth = __shfl_xor(own, 32, 64);
          const int rb = rt*32 + (q&3) + 8*(q>>2);
          sup[rb]   = kh ? oth : own;
          sup[rb+4] = kh ? own : oth;
        }
      }
      if (kh == 0){
        MIX_BODY(0)
      } else {
        MIX_BODY(1)
      }
    }
    __syncthreads();
  }

  // -------- output projection: y = h @ w_out + b_out --------
  {
    float wo0[4], wo1[4], wo2[4];
#pragma unroll
    for (int i=0;i<4;++i){
      const int k = i*64 + lane;
      wo0[i] = w_out[k*3]; wo1[i] = w_out[k*3+1]; wo2[i] = w_out[k*3+2];
    }
    const float bo0=b_out[0], bo1=b_out[1], bo2=b_out[2];
#pragma unroll 1
    for (int r = wid; r < RUSE; r += 8){
      const int s = r/17, j = r%17;
      float p0=0.f, p1=0.f, p2=0.f;
#pragma unroll
      for (int i=0;i<4;++i){
        const int k  = i*64 + lane;
        const int hb = (r << 9) + ((2*k) ^ ((r & 31) << 4));
        const float hv = bf2f(h_hi[hb>>1]) + bf2f(h_lo[hb>>1]);
        p0 += hv*wo0[i]; p1 += hv*wo1[i]; p2 += hv*wo2[i];
      }
#pragma unroll
      for (int m=32; m>0; m>>=1){
        p0 += __shfl_xor(p0, m, 64);
        p1 += __shfl_xor(p1, m, 64);
        p2 += __shfl_xor(p2, m, 64);
      }
      if (lane == 0){
        const size_t o = ((size_t)(wg*SPW+s)*17 + j)*3;
        out[o] = p0 + bo0; out[o+1] = p1 + bo1; out[o+2] = p2 + bo2;
      }
    }
  }
}

extern "C" void kernel_launch(void* const* d_in, const int* in_sizes, int n_in,
                              void* d_out, int out_size, void* d_ws, size_t ws_size,
                              hipStream_t stream)
{
  const float* x     = (const float*)d_in[0];
  const float* adj   = (const float*)d_in[1];
  const float* w_in  = (const float*)d_in[2];
  const float* b_in  = (const float*)d_in[3];
  const float* Ws    = (const float*)d_in[4];
  const float* bs    = (const float*)d_in[5];
  const float* w_out = (const float*)d_in[6];
  const float* b_out = (const float*)d_in[7];
  float* out = (float*)d_out;

  float* Ahat = (float*)d_ws;
  unsigned short* pret = (unsigned short*)((char*)d_ws + 4096);   // 1 MB

  hipLaunchKernelGGL(gcn_prep, dim3(1025), dim3(256), 0, stream, adj, Ws, Ahat, pret);
  hipLaunchKernelGGL(gcn_main, dim3(NWG), dim3(512), 0, stream,
                     x, w_in, b_in, bs, w_out, b_out, Ahat, pret, out);
}

// Round 4
// 625.520 us; speedup vs baseline: 2.2871x; 1.0007x over previous
//
#include <hip/hip_runtime.h>
#include <hip/hip_bf16.h>
#include <stdint.h>

// GCN pose: fused per-sample chain. 64*243=15552 samples, 17 joints, hidden 256, 4 layers.
// Split-bf16 (hi+lo) 3-pass MFMA. Round 4: kill scratch spills — sup[64] replaced by
// static acc refs + oth[2] float16 vectors (partner half via shfl_xor), all indices
// compile-time. SPW=3, 64KB LDS, 2 WG/CU, 4 waves/SIMD, B-frags direct from L2.

#define J17   17
#define HID   256
#define NLAY  4
#define NSAMP 15552
#define SPW   3          // samples per workgroup
#define RUSE  51         // SPW*17 used rows
#define RPAD  64         // padded rows (2 row-tiles of 32)
#define NWG   5184       // NSAMP/SPW exactly

typedef __attribute__((ext_vector_type(8)))  short  short8;   // 8 x bf16 fragment
typedef __attribute__((ext_vector_type(16))) float  float16;  // 32x32 accumulator

// fixed adjacency sparsity pattern (self + edges); values computed from adj input at runtime
static constexpr int OFS[18] = {0,3,6,9,11,13,17,21,24,27,29,31,35,39,42,45,47,49};
static constexpr int NBRF[49] = {
  0,1,2,  1,0,3,  2,0,4,  3,1,  4,2,
  5,6,7,11,  6,5,8,12,  7,5,9,  8,6,10,  9,7,  10,8,
  11,5,12,13, 12,6,11,14, 13,11,15, 14,12,16, 15,13, 16,14};

__device__ __forceinline__ unsigned short f2bf(float f){
  return __bfloat16_as_ushort(__float2bfloat16(f));   // single v_cvt, RNE
}
__device__ __forceinline__ float bf2f(unsigned short b){
  return __builtin_bit_cast(float, ((unsigned)b) << 16);
}

// ---------------- prep: A_hat + W split(hi/lo) + tile into fragment order ----------------
// pret layout (ushort): [layer][chunk(8)][hl(2)][u(4)][c(256)][j(8)]
//   element = split(W[layer][k][c], hl) with k = chunk*32 + (u>>1)*16 + (u&1)*8 + j
__global__ __launch_bounds__(256)
void gcn_prep(const float* __restrict__ adj, const float* __restrict__ Ws,
              float* __restrict__ Ahat, unsigned short* __restrict__ pret)
{
  if (blockIdx.x < 1024){
    const int e = blockIdx.x*256 + threadIdx.x;      // e = layer*65536 + k*256 + c
    const float w = Ws[e];
    const unsigned short hi = f2bf(w);
    const unsigned short lo = f2bf(w - bf2f(hi));
    const int layer = e >> 16, k = (e >> 8) & 255, c = e & 255;
    const int chunk = k >> 5, u = (k >> 3) & 3, j = k & 7;
    const size_t base = ((((size_t)(layer*8 + chunk)*2 + 0)*4 + u)*256 + c)*8 + j;
    pret[base]        = hi;
    pret[base + 8192] = lo;                          // hl stride = 4*256*8
  } else {
    for (int t = threadIdx.x; t < 289; t += 256){
      const int j = t/17, k = t%17;
      float dj = 1e-5f, dk = 1e-5f;
      for (int m=0;m<17;++m){ dj += adj[j*17+m]; dk += adj[k*17+m]; }
      Ahat[t] = adj[t] / (sqrtf(dj)*sqrtf(dk));
    }
  }
}

// C-fragment index decode for absolute row n (0..63):
//   n = (q&3) + 8*(q>>2) + 4*half + 32*rt  ->  q = (n&3) | (((n>>3)&3)<<2)
#define QIDX(n) (((n)&3) | ((((n)>>3)&3)<<2))
// support value for absolute row n, from own acc (if row's half == HH) else oth
#define SUPV(n, HH) (((((n)>>2)&1) == (HH)) ? acc[(n)>>5][QIDX(n)] : oth[(n)>>5][QIDX(n)])

// sparse mix for this half-wave's own C-layout rows (static rows -> static coeffs/regs)
#define MIX_BODY(HH) \
  _Pragma("unroll") \
  for (int rt_=0; rt_<2; ++rt_){ \
    _Pragma("unroll") \
    for (int q_=0; q_<16; ++q_){ \
      const int r_ = rt_*32 + (q_&3) + 8*(q_>>2) + 4*(HH); \
      if (r_ < RUSE){ \
        const int s_ = r_/17, j_ = r_%17; \
        float v_ = bsv; \
        _Pragma("unroll") \
        for (int t_=OFS[j_]; t_<OFS[j_+1]; ++t_) v_ += Ac[t_]*SUPV(s_*17 + NBRF[t_], HH); \
        const int hb_ = (r_ << 9) + ((2*c) ^ ((r_ & 31) << 4)); \
        const float o_ = fmaxf(v_, 0.0f) \
                       + bf2f(h_hi[hb_>>1]) + bf2f(h_lo[hb_>>1]); \
        const unsigned short hi_ = f2bf(o_); \
        h_hi[hb_>>1] = hi_; \
        h_lo[hb_>>1] = f2bf(o_ - bf2f(hi_)); \
      } \
    } \
  }

__global__ __launch_bounds__(512, 4)
void gcn_main(const float* __restrict__ x, const float* __restrict__ w_in,
              const float* __restrict__ b_in, const float* __restrict__ bs,
              const float* __restrict__ w_out, const float* __restrict__ b_out,
              const float* __restrict__ Ahat, const unsigned short* __restrict__ pret,
              float* __restrict__ out)
{
  __shared__ unsigned short h_hi[RPAD*HID];   // 32 KB, swizzled (r&31)<<4
  __shared__ unsigned short h_lo[RPAD*HID];   // 32 KB

  const int tid  = threadIdx.x;
  const int lane = tid & 63;
  const int wid  = tid >> 6;         // 0..7 : column-slice owner
  const int kh   = lane >> 5;
  const int l31  = lane & 31;
  const int c    = wid*32 + l31;     // this thread's output column
  const int wg   = blockIdx.x;

  const char* h_hi_b = (const char*)h_hi;
  const char* h_lo_b = (const char*)h_lo;

  // ---- B prefetch machinery: frags straight from global (L2-resident) ----
  const short8* pret8 = (const short8*)pret;            // 16B granules
  const int bbase = kh*256 + c;                          // per-thread offset
  short8 BA[4], BB[4];                                   // {s0hi, s0lo, s1hi, s1lo}
  auto loadB = [&](int lc, short8* dst){                 // lc = layer*8 + chunk (clamped)
    const short8* p = pret8 + (size_t)lc*2048 + bbase;
    dst[0] = p[0];
    dst[1] = p[1024];
    dst[2] = p[512];
    dst[3] = p[1536];
  };
  loadB(0, BA);                                          // hide L2 latency under prologue

  // sparse A_hat coefficients -> force SGPRs
  float Ac[49];
#pragma unroll
  for (int j=0;j<17;++j){
#pragma unroll
    for (int t=OFS[j]; t<OFS[j+1]; ++t){
      const float a = Ahat[j*17 + NBRF[t]];
      Ac[t] = __builtin_bit_cast(float,
                __builtin_amdgcn_readfirstlane(__builtin_bit_cast(int, a)));
    }
  }

  // -------- input projection directly in C-fragment ownership --------
  {
    const float bc  = b_in[c];
    const float wi0 = w_in[c], wi1 = w_in[256+c], wi2 = w_in[512+c];
#pragma unroll
    for (int rt=0; rt<2; ++rt){
#pragma unroll
      for (int q=0; q<16; ++q){
        const int r = rt*32 + (q&3) + 8*(q>>2) + 4*kh;
        float hv = 0.0f;
        if (r < RUSE){
          const int s = r/17, j = r%17;
          const size_t xb = ((size_t)(wg*SPW + s))*51 + j*3;
          hv = bc + x[xb]*wi0 + x[xb+1]*wi1 + x[xb+2]*wi2;
        }
        const int hb = (r << 9) + ((2*c) ^ ((r & 31) << 4));
        const unsigned short hi = f2bf(hv);
        h_hi[hb >> 1] = hi;
        h_lo[hb >> 1] = f2bf(hv - bf2f(hi));
      }
    }
  }
  __syncthreads();

  // ---------------------------- layers ----------------------------
  float16 acc[2];
  auto computeChunk = [&](int chunk, const short8* B){
#pragma unroll
    for (int sub=0; sub<2; ++sub){
      const int koff = (chunk*2 + sub)*32 + kh*16;       // byte offset of k-slice
      short8 Ahi[2], Alo[2];
#pragma unroll
      for (int rt=0; rt<2; ++rt){
        const int r   = rt*32 + l31;
        const int off = (r << 9) + (koff ^ ((r & 31) << 4));
        Ahi[rt] = *(const short8*)(h_hi_b + off);
        Alo[rt] = *(const short8*)(h_lo_b + off);
      }
      const short8 Bhi = B[sub*2], Blo = B[sub*2+1];
#pragma unroll
      for (int rt=0; rt<2; ++rt){
        acc[rt] = __builtin_amdgcn_mfma_f32_32x32x16_bf16(Ahi[rt], Bhi, acc[rt], 0,0,0);
        acc[rt] = __builtin_amdgcn_mfma_f32_32x32x16_bf16(Ahi[rt], Blo, acc[rt], 0,0,0);
        acc[rt] = __builtin_amdgcn_mfma_f32_32x32x16_bf16(Alo[rt], Bhi, acc[rt], 0,0,0);
      }
    }
  };

#pragma unroll 1
  for (int layer=0; layer<NLAY; ++layer){
#pragma unroll
    for (int rt=0; rt<2; ++rt)
#pragma unroll
    for (int q=0; q<16; ++q) acc[rt][q] = 0.0f;

#pragma unroll
    for (int cp=0; cp<4; ++cp){
      const int lc = layer*8 + cp*2;
      loadB(min(lc+1, 31), BB);
      computeChunk(cp*2,   BA);
      loadB(min(lc+2, 31), BA);                          // next chunk (or next layer c0)
      computeChunk(cp*2+1, BB);
    }
    __syncthreads();   // all A-frag reads done before anyone rewrites h

    // -------- graph mix + bias + relu + residual, update h --------
    // (h reads/writes below are owner-only -> race-free after the barrier)
    {
      const float bsv = bs[layer*256 + c];
      float16 oth[2];                                    // partner half's acc values
#pragma unroll
      for (int rt=0; rt<2; ++rt)
#pragma unroll
      for (int q=0; q<16; ++q)
        oth[rt][q] = __shfl_xor(acc[rt][q], 32, 64);
      if (kh == 0){
        MIX_BODY(0)
      } else {
        MIX_BODY(1)
      }
    }
    __syncthreads();
  }

  // -------- output projection: y = h @ w_out + b_out --------
  {
    float wo0[4], wo1[4], wo2[4];
#pragma unroll
    for (int i=0;i<4;++i){
      const int k = i*64 + lane;
      wo0[i] = w_out[k*3]; wo1[i] = w_out[k*3+1]; wo2[i] = w_out[k*3+2];
    }
    const float bo0=b_out[0], bo1=b_out[1], bo2=b_out[2];
#pragma unroll 1
    for (int r = wid; r < RUSE; r += 8){
      const int s = r/17, j = r%17;
      float p0=0.f, p1=0.f, p2=0.f;
#pragma unroll
      for (int i=0;i<4;++i){
        const int k  = i*64 + lane;
        const int hb = (r << 9) + ((2*k) ^ ((r & 31) << 4));
        const float hv = bf2f(h_hi[hb>>1]) + bf2f(h_lo[hb>>1]);
        p0 += hv*wo0[i]; p1 += hv*wo1[i]; p2 += hv*wo2[i];
      }
#pragma unroll
      for (int m=32; m>0; m>>=1){
        p0 += __shfl_xor(p0, m, 64);
        p1 += __shfl_xor(p1, m, 64);
        p2 += __shfl_xor(p2, m, 64);
      }
      if (lane == 0){
        const size_t o = ((size_t)(wg*SPW+s)*17 + j)*3;
        out[o] = p0 + bo0; out[o+1] = p1 + bo1; out[o+2] = p2 + bo2;
      }
    }
  }
}

extern "C" void kernel_launch(void* const* d_in, const int* in_sizes, int n_in,
                              void* d_out, int out_size, void* d_ws, size_t ws_size,
                              hipStream_t stream)
{
  const float* x     = (const float*)d_in[0];
  const float* adj   = (const float*)d_in[1];
  const float* w_in  = (const float*)d_in[2];
  const float* b_in  = (const float*)d_in[3];
  const float* Ws    = (const float*)d_in[4];
  const float* bs    = (const float*)d_in[5];
  const float* w_out = (const float*)d_in[6];
  const float* b_out = (const float*)d_in[7];
  float* out = (float*)d_out;

  float* Ahat = (float*)d_ws;
  unsigned short* pret = (unsigned short*)((char*)d_ws + 4096);   // 1 MB

  hipLaunchKernelGGL(gcn_prep, dim3(1025), dim3(256), 0, stream, adj, Ws, Ahat, pret);
  hipLaunchKernelGGL(gcn_main, dim3(NWG), dim3(512), 0, stream,
                     x, w_in, b_in, bs, w_out, b_out, Ahat, pret, out);
}

// Round 5
// 442.526 us; speedup vs baseline: 3.2328x; 1.4135x over previous
//
#include <hip/hip_runtime.h>
#include <hip/hip_bf16.h>
#include <stdint.h>

// GCN pose: fused per-sample chain. 64*243=15552 samples, 17 joints, hidden 256, 4 layers.
// Round 5: h in LDS as SINGLE bf16 (32 KB), W split hi/lo -> 2-pass MFMA
// (A*Whi + A*Wlo = A*W exactly in W). Input projection done as MFMA from a staged
// x-tile. B frags double-buffered from L2 at 16-reg granularity. SPW=3, 512 thr.

#define J17   17
#define HID   256
#define NLAY  4
#define NSAMP 15552
#define SPW   3
#define RUSE  51         // SPW*17 used rows
#define RPAD  64         // padded rows (2 row-tiles of 32)
#define NWG   5184       // NSAMP/SPW exactly

typedef __attribute__((ext_vector_type(4)))  short  short4v;
typedef __attribute__((ext_vector_type(8)))  short  short8;
typedef __attribute__((ext_vector_type(16))) float  float16;

static constexpr int OFS[18] = {0,3,6,9,11,13,17,21,24,27,29,31,35,39,42,45,47,49};
static constexpr int NBRF[49] = {
  0,1,2,  1,0,3,  2,0,4,  3,1,  4,2,
  5,6,7,11,  6,5,8,12,  7,5,9,  8,6,10,  9,7,  10,8,
  11,5,12,13, 12,6,11,14, 13,11,15, 14,12,16, 15,13, 16,14};

__device__ __forceinline__ unsigned short f2bf(float f){
  return __bfloat16_as_ushort(__float2bfloat16(f));   // v_cvt, RNE
}
__device__ __forceinline__ float bf2f(unsigned short b){
  return __builtin_bit_cast(float, ((unsigned)b) << 16);
}

// ---------------- prep ----------------
// pret_b (ushort, 1 MB): [t(64)][hl(2)][kh(2)][c(256)][j(8)]
//   value = split(W[t>>4][k][c], hl), k = (t&15)*16 + kh*8 + j
// pret_in (ushort, 8 KB): [kh(2)][c(256)][j(8)] = bf16(w_in[k][c]), k = kh*8+j (<3 else 0)
__global__ __launch_bounds__(256)
void gcn_prep(const float* __restrict__ adj, const float* __restrict__ Ws,
              const float* __restrict__ w_in,
              float* __restrict__ Ahat, unsigned short* __restrict__ pret_in,
              unsigned short* __restrict__ pret_b)
{
  if (blockIdx.x < 1024){
    const int e  = blockIdx.x*256 + threadIdx.x;      // 0..262143
    const int j  = e & 7, cc = (e >> 3) & 255, khh = (e >> 11) & 1, t = e >> 12;
    const int k  = (t & 15)*16 + khh*8 + j;
    const float w = Ws[(t >> 4)*65536 + k*256 + cc];
    const unsigned short hi = f2bf(w);
    const int base = (t*4 + khh)*2048 + cc*8 + j;     // hl=0 slot
    pret_b[base]        = hi;
    pret_b[base + 4096] = f2bf(w - bf2f(hi));         // hl=1
  } else {
    const int tid = threadIdx.x;
    for (int e = tid; e < 4096; e += 256){
      const int j = e & 7, cc = (e >> 3) & 255, khh = e >> 11;
      const int k = khh*8 + j;
      pret_in[e] = (k < 3) ? f2bf(w_in[k*256 + cc]) : (unsigned short)0;
    }
    for (int t = tid; t < 289; t += 256){
      const int j = t/17, k2 = t%17;
      float dj = 1e-5f, dk = 1e-5f;
      for (int m=0;m<17;++m){ dj += adj[j*17+m]; dk += adj[k2*17+m]; }
      Ahat[t] = adj[t] / (sqrtf(dj)*sqrtf(dk));
    }
  }
}

// C-fragment decode: row n = (q&3) + 8*(q>>2) + 4*half + 32*rt
#define QIDX(n) (((n)&3) | ((((n)>>3)&3)<<2))
#define SUPV(n, HH) (((((n)>>2)&1) == (HH)) ? acc[(n)>>5][QIDX(n)] : oth[(n)>>5][QIDX(n)])

#define MIX_BODY(HH) \
  _Pragma("unroll") \
  for (int rt_=0; rt_<2; ++rt_){ \
    _Pragma("unroll") \
    for (int q_=0; q_<16; ++q_){ \
      const int r_ = rt_*32 + (q_&3) + 8*(q_>>2) + 4*(HH); \
      if (r_ < RUSE){ \
        const int s_ = r_/17, j_ = r_%17; \
        float v_ = bsv; \
        _Pragma("unroll") \
        for (int t_=OFS[j_]; t_<OFS[j_+1]; ++t_) v_ += Ac[t_]*SUPV(s_*17 + NBRF[t_], HH); \
        const int hb_ = (r_ << 9) + ((2*c) ^ ((r_ & 31) << 4)); \
        const float o_ = fmaxf(v_, 0.0f) + bf2f(h[hb_>>1]); \
        h[hb_>>1] = f2bf(o_); \
      } \
    } \
  }

__global__ __launch_bounds__(512, 4)
void gcn_main(const float* __restrict__ x, const float* __restrict__ b_in,
              const float* __restrict__ bs, const float* __restrict__ w_out,
              const float* __restrict__ b_out, const float* __restrict__ Ahat,
              const unsigned short* __restrict__ pret_in,
              const unsigned short* __restrict__ pret_b,
              float* __restrict__ out)
{
  __shared__ unsigned short h[RPAD*HID];    // 32 KB, swizzled (r&31)<<4 on bytes
  __shared__ unsigned short xt[RPAD*32];    // 4 KB x-tile, rows x k(32)

  const int tid  = threadIdx.x;
  const int lane = tid & 63;
  const int wid  = tid >> 6;
  const int kh   = lane >> 5;
  const int l31  = lane & 31;
  const int c    = wid*32 + l31;
  const int wg   = blockIdx.x;

  const char* h_b = (const char*)h;

  // ---- B prefetch: frags straight from global (L2-resident) ----
  const unsigned short* pb = pret_b + kh*2048 + c*8;
  short8 BA[2], BB[2];                       // {Whi, Wlo} for one k-step
  auto loadB = [&](int t, short8* d){
    const unsigned short* p = pb + t*8192;
    d[0] = *(const short8*)p;
    d[1] = *(const short8*)(p + 4096);
  };
  loadB(0, BA);
  const short8 BI = *(const short8*)(pret_in + kh*2048 + c*8);

  // sparse A_hat coefficients -> SGPRs
  float Ac[49];
#pragma unroll
  for (int j=0;j<17;++j){
#pragma unroll
    for (int t=OFS[j]; t<OFS[j+1]; ++t){
      const float a = Ahat[j*17 + NBRF[t]];
      Ac[t] = __builtin_bit_cast(float,
                __builtin_amdgcn_readfirstlane(__builtin_bit_cast(int, a)));
    }
  }

  // ---- stage x tile: xt[r][k], k<3 real else 0 ----
  {
    const int r = tid >> 3, k4 = (tid & 7) << 2;
    short4v v = (short4v)0;
    if (r < RUSE && k4 == 0){
      const int s = r/17, j = r - s*17;
      const float* xb = x + (size_t)(wg*SPW + s)*51 + j*3;
      v.x = (short)f2bf(xb[0]); v.y = (short)f2bf(xb[1]); v.z = (short)f2bf(xb[2]);
    }
    *(short4v*)(xt + r*32 + k4) = v;
  }
  __syncthreads();

  // ---- input projection as MFMA: h0 = x @ w_in + b_in ----
  float16 acc[2];
  {
    const float bc = b_in[c];
#pragma unroll
    for (int rt=0; rt<2; ++rt)
#pragma unroll
    for (int q=0; q<16; ++q) acc[rt][q] = bc;
#pragma unroll
    for (int rt=0; rt<2; ++rt){
      const short8 Ax = *(const short8*)(xt + (rt*32 + l31)*32 + kh*8);
      acc[rt] = __builtin_amdgcn_mfma_f32_32x32x16_bf16(Ax, BI, acc[rt], 0,0,0);
    }
#pragma unroll
    for (int rt=0; rt<2; ++rt)
#pragma unroll
    for (int q=0; q<16; ++q){
      const int r  = rt*32 + (q&3) + 8*(q>>2) + 4*kh;
      const int hb = (r << 9) + ((2*c) ^ ((r & 31) << 4));
      h[hb >> 1] = f2bf(acc[rt][q]);
    }
  }
  __syncthreads();

  // ---- layers ----
  auto step = [&](int ksl, const short8* B){   // ksl = k-step within layer (0..15)
    short8 Ah[2];
#pragma unroll
    for (int rt=0; rt<2; ++rt){
      const int r   = rt*32 + l31;
      const int off = (r << 9) + ((ksl*32 + kh*16) ^ ((r & 31) << 4));
      Ah[rt] = *(const short8*)(h_b + off);
    }
#pragma unroll
    for (int rt=0; rt<2; ++rt){
      acc[rt] = __builtin_amdgcn_mfma_f32_32x32x16_bf16(Ah[rt], B[0], acc[rt], 0,0,0);
      acc[rt] = __builtin_amdgcn_mfma_f32_32x32x16_bf16(Ah[rt], B[1], acc[rt], 0,0,0);
    }
  };

#pragma unroll 1
  for (int layer=0; layer<NLAY; ++layer){
#pragma unroll
    for (int rt=0; rt<2; ++rt)
#pragma unroll
    for (int q=0; q<16; ++q) acc[rt][q] = 0.0f;

    const int t0 = layer*16;
#pragma unroll
    for (int ks=0; ks<16; ks+=2){
      loadB(t0 + ks + 1, BB);
      step(ks, BA);
      loadB(min(t0 + ks + 2, 63), BA);       // next k-step / next layer's k0
      step(ks + 1, BB);
    }
    __syncthreads();   // all A-frag reads done before mix rewrites h

    // ---- graph mix + bias + relu + residual ----
    {
      const float bsv = bs[layer*256 + c];
      float16 oth[2];
#pragma unroll
      for (int rt=0; rt<2; ++rt)
#pragma unroll
      for (int q=0; q<16; ++q)
        oth[rt][q] = __shfl_xor(acc[rt][q], 32, 64);
      if (kh == 0){
        MIX_BODY(0)
      } else {
        MIX_BODY(1)
      }
    }
    __syncthreads();
  }

  // ---- output projection: y = h @ w_out + b_out ----
  {
    float wo0[4], wo1[4], wo2[4];
#pragma unroll
    for (int i=0;i<4;++i){
      const int k = i*64 + lane;
      wo0[i] = w_out[k*3]; wo1[i] = w_out[k*3+1]; wo2[i] = w_out[k*3+2];
    }
    const float bo0=b_out[0], bo1=b_out[1], bo2=b_out[2];
#pragma unroll 1
    for (int r = wid; r < RUSE; r += 8){
      const int s = r/17, j = r - s*17;
      float p0=0.f, p1=0.f, p2=0.f;
#pragma unroll
      for (int i=0;i<4;++i){
        const int k  = i*64 + lane;
        const int hb = (r << 9) + ((2*k) ^ ((r & 31) << 4));
        const float hv = bf2f(h[hb>>1]);
        p0 += hv*wo0[i]; p1 += hv*wo1[i]; p2 += hv*wo2[i];
      }
#pragma unroll
      for (int m=32; m>0; m>>=1){
        p0 += __shfl_xor(p0, m, 64);
        p1 += __shfl_xor(p1, m, 64);
        p2 += __shfl_xor(p2, m, 64);
      }
      if (lane == 0){
        const size_t o = ((size_t)(wg*SPW+s)*17 + j)*3;
        out[o] = p0 + bo0; out[o+1] = p1 + bo1; out[o+2] = p2 + bo2;
      }
    }
  }
}

extern "C" void kernel_launch(void* const* d_in, const int* in_sizes, int n_in,
                              void* d_out, int out_size, void* d_ws, size_t ws_size,
                              hipStream_t stream)
{
  const float* x     = (const float*)d_in[0];
  const float* adj   = (const float*)d_in[1];
  const float* w_in  = (const float*)d_in[2];
  const float* b_in  = (const float*)d_in[3];
  const float* Ws    = (const float*)d_in[4];
  const float* bs    = (const float*)d_in[5];
  const float* w_out = (const float*)d_in[6];
  const float* b_out = (const float*)d_in[7];
  float* out = (float*)d_out;

  float*          Ahat    = (float*)d_ws;
  unsigned short* pret_in = (unsigned short*)((char*)d_ws + 4096);    // 8 KB
  unsigned short* pret_b  = (unsigned short*)((char*)d_ws + 16384);   // 1 MB

  hipLaunchKernelGGL(gcn_prep, dim3(1025), dim3(256), 0, stream,
                     adj, Ws, w_in, Ahat, pret_in, pret_b);
  hipLaunchKernelGGL(gcn_main, dim3(NWG), dim3(512), 0, stream,
                     x, b_in, bs, w_out, b_out, Ahat, pret_in, pret_b, out);
}